// Round 2
// 340.452 us; speedup vs baseline: 1.1909x; 1.1909x over previous
//
#include <hip/hip_runtime.h>

#define N_ 16
#define T_ 8
#define L_ 197
#define H_ 12
#define D_ 64
#define Q_ 196
#define C_ 768
#define KP 224          // padded K/pos dimension (7 x 32)
#define ENT 1792        // 8 dchunks * 224 pos, 16B entries per (nt,h) plane
#define ATS 216         // attn epilogue LDS row stride (ushorts)
#define APLANE 2112     // mix: As plane stride bytes (2048 + 64 skew)

typedef unsigned short ushort_t;
typedef __bf16 bf16x8 __attribute__((ext_vector_type(8)));
typedef float floatx4 __attribute__((ext_vector_type(4)));

// async global->LDS, 16B per lane, dst = uniform base + lane*16
#define GLD_LDS16(g, l)                                                    \
  __builtin_amdgcn_global_load_lds(                                        \
      (const __attribute__((address_space(1))) void*)(g),                  \
      (__attribute__((address_space(3))) void*)(l), 16, 0, 0)

static __device__ inline ushort_t f2bf(float x) {
  unsigned int u = __float_as_uint(x);
  u += 0x7fffu + ((u >> 16) & 1u);       // RNE
  return (ushort_t)(u >> 16);
}
static __device__ inline unsigned int pack2(float a, float b) {
  return (unsigned int)f2bf(a) | ((unsigned int)f2bf(b) << 16);
}

// ------------- Pass 0: q,k fp32 -> bf16 planes [nt][h][dc 8][pos 224] ------
__global__ __launch_bounds__(256) void convert_kernel(
    const float* __restrict__ q, const float* __restrict__ k,
    uint4* __restrict__ qb, uint4* __restrict__ kb) {
  const int nt  = blockIdx.x;      // 0..127
  const int pc  = blockIdx.y;      // 0..6
  const int inp = blockIdx.z;      // 0 = q, 1 = k
  const int tid = threadIdx.x;
  const int pos0 = pc * 28;

  const float* src = inp ? k : q;
  const float sc = inp ? 1.f : 0.125f;
  uint4* dst = inp ? kb : qb;

  __shared__ uint2 lds[28][194];

  #pragma unroll
  for (int r = 0; r < 21; r++) {
    int e = tid + 256 * r;                 // < 5376
    int row = e / 192, col = e - row * 192;
    float4 v = *(const float4*)(src + ((size_t)nt * L_ + 1 + pos0 + row) * (H_ * D_) + col * 4);
    uint2 p;
    p.x = pack2(v.x * sc, v.y * sc);
    p.y = pack2(v.z * sc, v.w * sc);
    lds[row][col] = p;
  }
  __syncthreads();

  #pragma unroll
  for (int r = 0; r < 11; r++) {
    int e = tid + 256 * r;
    if (e < 2688) {
      int hd = e / 28, p = e - hd * 28;    // hd = h*8+dc
      uint2 a = lds[p][hd * 2];
      uint2 b = lds[p][hd * 2 + 1];
      int h = hd >> 3, dc = hd & 7;
      uint4 o; o.x = a.x; o.y = a.y; o.z = b.x; o.w = b.y;
      dst[((size_t)nt * H_ + h) * ENT + dc * KP + pos0 + p] = o;
    }
  }
}

// ------------- Stage 1: A[qi][nt][k] = mean_h softmax_k(QK^T/8), bf16 ------
// 1D grid 896, XCD-swizzled. K double-buffered in LDS via global_load_lds;
// raw s_barrier + counted vmcnt(9) keeps the next head's DMA (7 loads) and
// Q-frag loads (2) in flight across barriers (T3+T4). Q ping-pongs between
// two named register sets (static indexing only).
__global__ __launch_bounds__(256, 2) void attn_kernel(
    const uint4* __restrict__ qb, const uint4* __restrict__ kb,
    ushort_t* __restrict__ A1, ushort_t* __restrict__ A2) {
  const int lin  = blockIdx.x;          // 0..895
  const int xcd  = lin & 7;
  const int slot = lin >> 3;            // 0..111
  const int g    = (slot >> 2) * 8 + xcd;   // K-group 0..223
  const int b    = slot & 3;            // q-row block of 64
  const int half = g / 112;
  const int nt   = g - half * 112;
  const int n  = nt / 7, tp = nt % 7;
  const int tq = (half == 0) ? tp + 1 : tp;
  const int tk = (half == 0) ? tp     : tp + 1;
  const int ntq = n * T_ + tq;
  const int ntk = n * T_ + tk;

  const uint4* qpl = qb + (size_t)ntq * H_ * ENT;
  const uint4* kpl = kb + (size_t)ntk * H_ * ENT;
  ushort_t* Ah = (half == 0) ? A1 : A2;

  __shared__ __align__(16) uint4 ks[2][ENT];   // 2 x 28 KB double buffer
  ushort_t* at = (ushort_t*)ks;                // epilogue alias (27.6 KB, in ks[0])

  const int tid  = threadIdx.x;
  const int lane = tid & 63;
  const int wv   = tid >> 6;
  const int quad = lane >> 4;
  const int l15  = lane & 15;
  const int qi_b = 64 * b + 16 * wv;

  float accA[13][4];
  #pragma unroll
  for (int t = 0; t < 13; t++)
    #pragma unroll
    for (int r = 0; r < 4; r++) accA[t][r] = 0.f;

  // per-wave K DMA for head h into buffer bufp (7 vmem ops / wave)
  auto stage = [&](int h, uint4* bufp) {
    #pragma unroll
    for (int r = 0; r < 7; r++)
      GLD_LDS16(kpl + (size_t)h * ENT + 256 * r + 64 * wv + lane,
                (char*)bufp + (256 * r + 64 * wv) * 16);
  };
  // Q fragments for head h (2 vmem ops / lane)
  auto loadq = [&](int h, bf16x8* qf) {
    #pragma unroll
    for (int kk = 0; kk < 2; kk++)
      qf[kk] = *(const bf16x8*)&qpl[(size_t)h * ENT + (quad + 4 * kk) * KP + qi_b + l15];
  };

  // one head: wait(own DMA(h)+Q(h) landed, keep next head's 9 in flight) ->
  // barrier -> MFMA from bufp -> barrier -> issue head h+2 into same buffer
  // (parity) -> softmax (overlaps the in-flight DMA).
  auto headbody = [&](int h, uint4* bufp, bf16x8* qf, bool lastwait) {
    if (lastwait) asm volatile("s_waitcnt vmcnt(0)" ::: "memory");
    else          asm volatile("s_waitcnt vmcnt(9)" ::: "memory");
    __builtin_amdgcn_s_barrier();
    asm volatile("" ::: "memory");       // no LDS read hoists above barrier

    const ushort_t* bu = (const ushort_t*)bufp;
    floatx4 S[13];
    #pragma unroll
    for (int t = 0; t < 13; t++) S[t] = (floatx4){0.f, 0.f, 0.f, 0.f};
    #pragma unroll
    for (int kk = 0; kk < 2; kk++)
      #pragma unroll
      for (int t = 0; t < 13; t++) {
        bf16x8 bbv = *(const bf16x8*)&bu[((quad + 4 * kk) * KP + 16 * t + l15) * 8];
        S[t] = __builtin_amdgcn_mfma_f32_16x16x32_bf16(qf[kk], bbv, S[t], 0, 0, 0);
      }

    asm volatile("" ::: "memory");       // no LDS read sinks below barrier
    __builtin_amdgcn_s_barrier();        // all waves done reading bufp
    if (h + 2 < H_) {                    // prefetch 2 heads ahead
      loadq(h + 2, qf);
      stage(h + 2, bufp);
      // keep the 9-op issue cluster together; nothing drifts across softmax
      __builtin_amdgcn_sched_barrier(0);
    }

    // softmax over k (196 valid), accumulate P/rowsum (pure VALU, overlaps DMA)
    #pragma unroll
    for (int r = 0; r < 4; r++) {
      float s = 0.f;
      #pragma unroll
      for (int t = 0; t < 13; t++) {
        float e_ = (t == 12 && l15 >= 4) ? 0.f : __expf(S[t][r]);
        S[t][r] = e_;
        s += e_;
      }
      #pragma unroll
      for (int off = 1; off < 16; off <<= 1) s += __shfl_xor(s, off);
      float inv = 1.f / s;
      #pragma unroll
      for (int t = 0; t < 13; t++) accA[t][r] += S[t][r] * inv;
    }
  };

  // prologue: heads 0 and 1 in flight. Issue-order MUST be {Q0,D0} then
  // {Q1,D1} for the vmcnt(9) count to drain exactly head 0 at the first
  // wait — sched_barrier(0) pins the groups (plain Q loads could otherwise
  // hoist above the LDS-DMA builtins).
  bf16x8 qfA[2], qfB[2];
  loadq(0, qfA); stage(0, ks[0]);
  __builtin_amdgcn_sched_barrier(0);
  loadq(1, qfB); stage(1, ks[1]);
  __builtin_amdgcn_sched_barrier(0);

  #pragma unroll 1
  for (int hh = 0; hh < 6; hh++) {
    headbody(2 * hh,     ks[0], qfA, false);
    headbody(2 * hh + 1, ks[1], qfB, hh == 5);
  }

  // epilogue: transpose accA via LDS (wave-private rows), uint4 stores
  const float s12 = 1.f / 12.f;
  #pragma unroll
  for (int t = 0; t < 13; t++)
    #pragma unroll
    for (int r = 0; r < 4; r++)
      at[(16 * wv + 4 * quad + r) * ATS + 16 * t + l15] = f2bf(accA[t][r] * s12);
  #pragma unroll
  for (int i = 0; i < 7; i++) {
    int e = lane + 64 * i;             // 16 rows x 26 uint4 = 416
    if (e < 416) {
      int row = e / 26, col = e - row * 26;
      uint4 v = *(const uint4*)&at[(16 * wv + row) * ATS + col * 8];
      int qi = qi_b + row;
      if (qi < Q_)
        *(uint4*)(Ah + ((size_t)qi * (N_ * T_) + ntq) * KP + col * 8) = v;
    }
  }
}

// ------------- Stage 2: out[nt,qi,c] = sum_half A_h[qi] @ gather(W_h) ------
// grid (6 c-tiles of 128, 196 qi), block 256. As via DMA (dbuf, skewed
// planes); W gather is wave-private -> ONE barrier per chunk.
__global__ __launch_bounds__(256, 4) void mix_kernel(
    const ushort_t* __restrict__ A1, const ushort_t* __restrict__ A2,
    const float* __restrict__ w1, const float* __restrict__ w2,
    const int* __restrict__ idx, float* __restrict__ out) {
  const int ct = blockIdx.x;   // 0..5
  const int qi = blockIdx.y;   // 0..195
  const int tid  = threadIdx.x;
  const int lane = tid & 63;
  const int wv   = tid >> 6;
  const int quad = lane >> 4;
  const int l15  = lane & 15;
  const int p    = lane >> 2;  // k-pair 0..15
  const int cq   = lane & 3;   // c-chunk slot

  __shared__ __align__(16) char As[2][4 * APLANE];   // 2 x 8448 B
  __shared__ ushort_t Ws[128][40];                   // wave-private rows

  // idx regs: this lane's two k-rows per chunk (clamped; A=0 kills pad cols)
  int idxr0[7], idxr1[7];
  #pragma unroll
  for (int kc = 0; kc < 7; kc++) {
    int off = 32 * kc + 2 * p;
    if (off > 194) off = 194;
    int2 pr = *(const int2*)(idx + (size_t)qi * Q_ + off);
    idxr0[kc] = pr.x; idxr1[kc] = pr.y;
  }

  floatx4 acc[8][2];
  #pragma unroll
  for (int mt = 0; mt < 8; mt++)
    #pragma unroll
    for (int u = 0; u < 2; u++) acc[mt][u] = (floatx4){0.f, 0.f, 0.f, 0.f};

  float4 pw[2][2];   // [k-offset j][c-chunk u]
  const int cbase = ct * 128 + wv * 32;

  // ---- preload chunk 0 ----
  {
    const ushort_t* Ah_ = A1;
    #pragma unroll
    for (int r = 0; r < 2; r++)
      GLD_LDS16(Ah_ + ((size_t)qi * 128 + r * 64 + lane) * KP + wv * 8,
                As[0] + wv * APLANE + r * 1024);
    #pragma unroll
    for (int j = 0; j < 2; j++)
      #pragma unroll
      for (int u = 0; u < 2; u++)
        pw[j][u] = *(const float4*)(w1 + (size_t)(j ? idxr1[0] : idxr0[0]) * C_ +
                                    cbase + (cq + 4 * u) * 4);
  }

  #pragma unroll
  for (int ht = 0; ht < 14; ht++) {
    const int half = ht / 7, kc = ht % 7;
    __syncthreads();                 // As[ht&1] DMA + pw gather drained

    // commit this chunk's W (wave-private -> no barrier needed)
    #pragma unroll
    for (int u = 0; u < 2; u++) {
      const float* f0 = (const float*)&pw[0][u];
      const float* f1 = (const float*)&pw[1][u];
      #pragma unroll
      for (int e = 0; e < 4; e++)
        *(unsigned int*)&Ws[wv * 32 + (cq + 4 * u) * 4 + e][2 * p] = pack2(f0[e], f1[e]);
    }

    // issue next chunk's A-DMA + W-gather (in flight through the MFMA phase)
    if (ht + 1 < 14) {
      const int nh = (ht + 1) / 7, nk = (ht + 1) % 7;
      const ushort_t* Ah_ = nh ? A2 : A1;
      const float* w_ = nh ? w2 : w1;
      #pragma unroll
      for (int r = 0; r < 2; r++)
        GLD_LDS16(Ah_ + ((size_t)qi * 128 + r * 64 + lane) * KP + 32 * nk + wv * 8,
                  As[(ht + 1) & 1] + wv * APLANE + r * 1024);
      int r0 = idxr0[nk], r1 = idxr1[nk];
      #pragma unroll
      for (int u = 0; u < 2; u++) {
        pw[0][u] = *(const float4*)(w_ + (size_t)r0 * C_ + cbase + (cq + 4 * u) * 4);
        pw[1][u] = *(const float4*)(w_ + (size_t)r1 * C_ + cbase + (cq + 4 * u) * 4);
      }
    }

    // MFMA phase: LDS only
    const char* ab = As[ht & 1];
    bf16x8 bfv[2];
    #pragma unroll
    for (int u = 0; u < 2; u++)
      bfv[u] = *(const bf16x8*)&Ws[wv * 32 + 16 * u + l15][8 * quad];
    #pragma unroll
    for (int mt = 0; mt < 8; mt++) {
      bf16x8 a = *(const bf16x8*)(ab + quad * APLANE + (16 * mt + l15) * 16);
      acc[mt][0] = __builtin_amdgcn_mfma_f32_16x16x32_bf16(a, bfv[0], acc[mt][0], 0, 0, 0);
      acc[mt][1] = __builtin_amdgcn_mfma_f32_16x16x32_bf16(a, bfv[1], acc[mt][1], 0, 0, 0);
    }
  }

  #pragma unroll
  for (int u = 0; u < 2; u++) {
    const int c = ct * 128 + 32 * wv + 16 * u + l15;
    #pragma unroll
    for (int mt = 0; mt < 8; mt++)
      #pragma unroll
      for (int r = 0; r < 4; r++) {
        int m = 16 * mt + 4 * quad + r;
        out[((size_t)m * L_ + 1 + qi) * C_ + c] = acc[mt][u][r];
      }
  }
  if (qi == 0) {
    #pragma unroll
    for (int u = 0; u < 2; u++) {
      const int c = ct * 128 + 32 * wv + 16 * u + l15;
      #pragma unroll
      for (int mt = 0; mt < 8; mt++)
        #pragma unroll
        for (int r = 0; r < 4; r++) {
          int m = 16 * mt + 4 * quad + r;
          out[(size_t)m * L_ * C_ + c] = 0.f;
        }
    }
  }
}

extern "C" void kernel_launch(void* const* d_in, const int* in_sizes, int n_in,
                              void* d_out, int out_size, void* d_ws, size_t ws_size,
                              hipStream_t stream) {
  const float* q  = (const float*)d_in[0];
  const float* k  = (const float*)d_in[1];
  const float* w1 = (const float*)d_in[2];
  const float* w2 = (const float*)d_in[3];
  const int* idx  = (const int*)d_in[4];
  float* out = (float*)d_out;

  const size_t plane_tot = (size_t)(N_ * T_) * H_ * ENT;   // uint4 entries
  uint4* qb = (uint4*)d_ws;
  uint4* kb = qb + plane_tot;
  ushort_t* A1 = (ushort_t*)(kb + plane_tot);
  size_t Aelems = (size_t)Q_ * (N_ * T_) * KP;
  ushort_t* A2 = A1 + Aelems;

  // zero A buffers: covers k-pad cols and the empty t-slots
  hipMemsetAsync(A1, 0, Aelems * 2 * sizeof(ushort_t), stream);

  convert_kernel<<<dim3(N_ * T_, 7, 2), 256, 0, stream>>>(q, k, qb, kb);
  attn_kernel<<<dim3(896), 256, 0, stream>>>(qb, kb, A1, A2);
  mix_kernel<<<dim3(6, Q_), 256, 0, stream>>>(A1, A2, w1, w2, idx, out);
}

// Round 3
// 338.342 us; speedup vs baseline: 1.1983x; 1.0062x over previous
//
#include <hip/hip_runtime.h>

#define N_ 16
#define T_ 8
#define L_ 197
#define H_ 12
#define D_ 64
#define Q_ 196
#define C_ 768
#define KP 224          // padded K/pos dimension (7 x 32)
#define ENT 1792        // 8 dchunks * 224 pos, 16B entries per (nt,h) plane
#define ATS 216         // attn epilogue LDS row stride (ushorts)
#define APLANE 2112     // mix: As plane stride bytes (2048 + 64 skew)

typedef unsigned short ushort_t;
typedef __bf16 bf16x8 __attribute__((ext_vector_type(8)));
typedef float floatx4 __attribute__((ext_vector_type(4)));

// async global->LDS, 16B per lane, dst = uniform base + lane*16
#define GLD_LDS16(g, l)                                                    \
  __builtin_amdgcn_global_load_lds(                                        \
      (const __attribute__((address_space(1))) void*)(g),                  \
      (__attribute__((address_space(3))) void*)(l), 16, 0, 0)

static __device__ inline ushort_t f2bf(float x) {
  unsigned int u = __float_as_uint(x);
  u += 0x7fffu + ((u >> 16) & 1u);       // RNE
  return (ushort_t)(u >> 16);
}
static __device__ inline unsigned int pack2(float a, float b) {
  return (unsigned int)f2bf(a) | ((unsigned int)f2bf(b) << 16);
}

// ------------- Pass 0: q,k fp32 -> bf16 planes [nt][h][dc 8][pos 224] ------
// One block per (nt, h, q|k) plane. Thread reads 8 consecutive d-floats
// (32B aligned, 8 lanes tile one position's 256B h-slice), packs a uint4,
// stages via XOR-swizzled LDS (conflict-free both phases), then streams the
// 28KB output plane contiguously (1KB/wave stores). Pad pos 196..223 = 0.
__global__ __launch_bounds__(256) void convert_kernel(
    const float* __restrict__ q, const float* __restrict__ k,
    uint4* __restrict__ qb, uint4* __restrict__ kb) {
  const int nt  = blockIdx.x;      // 0..127
  const int h   = blockIdx.y;      // 0..11
  const int inp = blockIdx.z;      // 0 = q, 1 = k
  const int tid = threadIdx.x;

  const float* src = inp ? k : q;
  const float sc = inp ? 1.f : 0.125f;
  uint4* dst = (inp ? kb : qb) + ((size_t)nt * H_ + h) * ENT;

  __shared__ __align__(16) uint4 lds[8 * KP];   // 28 KB: [dc][pos swizzled]

  const float* base = src + ((size_t)nt * L_ + 1) * (H_ * D_) + h * D_;

  #pragma unroll
  for (int r = 0; r < 7; r++) {
    int e = tid + 256 * r;               // < 1792; valid < 1568 (196 pos * 8 dc)
    if (e < 1568) {
      int pos = e >> 3, dc = e & 7;
      const float* p = base + (size_t)pos * (H_ * D_) + dc * 8;
      float4 a  = *(const float4*)p;
      float4 bv = *(const float4*)(p + 4);
      uint4 o;
      o.x = pack2(a.x * sc, a.y * sc);
      o.y = pack2(a.z * sc, a.w * sc);
      o.z = pack2(bv.x * sc, bv.y * sc);
      o.w = pack2(bv.z * sc, bv.w * sc);
      lds[dc * KP + ((pos & ~7) | ((pos ^ dc) & 7))] = o;
    }
  }
  __syncthreads();

  #pragma unroll
  for (int r = 0; r < 7; r++) {
    int e = tid + 256 * r;               // output entry, 0..1791
    int dc = e / KP, pos = e - dc * KP;
    uint4 v;
    if (pos < 196) v = lds[dc * KP + ((pos & ~7) | ((pos ^ dc) & 7))];
    else           v = (uint4){0u, 0u, 0u, 0u};
    dst[e] = v;
  }
}

// ------------- Stage 1: A[qi][nt][k] = mean_h softmax_k(QK^T/8), bf16 ------
// 1D grid 896, XCD-swizzled. K double-buffered in LDS via global_load_lds;
// raw s_barrier + counted vmcnt(9) keeps the next head's DMA (7 loads) and
// Q-frag loads (2) in flight across barriers (T3+T4). Q ping-pongs between
// two named register sets (static indexing only).
__global__ __launch_bounds__(256, 2) void attn_kernel(
    const uint4* __restrict__ qb, const uint4* __restrict__ kb,
    ushort_t* __restrict__ A1, ushort_t* __restrict__ A2) {
  const int lin  = blockIdx.x;          // 0..895
  const int xcd  = lin & 7;
  const int slot = lin >> 3;            // 0..111
  const int g    = (slot >> 2) * 8 + xcd;   // K-group 0..223
  const int b    = slot & 3;            // q-row block of 64
  const int half = g / 112;
  const int nt   = g - half * 112;
  const int n  = nt / 7, tp = nt % 7;
  const int tq = (half == 0) ? tp + 1 : tp;
  const int tk = (half == 0) ? tp     : tp + 1;
  const int ntq = n * T_ + tq;
  const int ntk = n * T_ + tk;

  const uint4* qpl = qb + (size_t)ntq * H_ * ENT;
  const uint4* kpl = kb + (size_t)ntk * H_ * ENT;
  ushort_t* Ah = (half == 0) ? A1 : A2;

  __shared__ __align__(16) uint4 ks[2][ENT];   // 2 x 28 KB double buffer
  ushort_t* at = (ushort_t*)ks;                // epilogue alias (27.6 KB, in ks[0])

  const int tid  = threadIdx.x;
  const int lane = tid & 63;
  const int wv   = tid >> 6;
  const int quad = lane >> 4;
  const int l15  = lane & 15;
  const int qi_b = 64 * b + 16 * wv;

  float accA[13][4];
  #pragma unroll
  for (int t = 0; t < 13; t++)
    #pragma unroll
    for (int r = 0; r < 4; r++) accA[t][r] = 0.f;

  // per-wave K DMA for head h into buffer bufp (7 vmem ops / wave)
  auto stage = [&](int h, uint4* bufp) {
    #pragma unroll
    for (int r = 0; r < 7; r++)
      GLD_LDS16(kpl + (size_t)h * ENT + 256 * r + 64 * wv + lane,
                (char*)bufp + (256 * r + 64 * wv) * 16);
  };
  // Q fragments for head h (2 vmem ops / lane)
  auto loadq = [&](int h, bf16x8* qf) {
    #pragma unroll
    for (int kk = 0; kk < 2; kk++)
      qf[kk] = *(const bf16x8*)&qpl[(size_t)h * ENT + (quad + 4 * kk) * KP + qi_b + l15];
  };

  // one head: wait(own DMA(h)+Q(h) landed, keep next head's 9 in flight) ->
  // barrier -> MFMA from bufp -> barrier -> issue head h+2 into same buffer
  // (parity) -> softmax (overlaps the in-flight DMA).
  auto headbody = [&](int h, uint4* bufp, bf16x8* qf, bool lastwait) {
    if (lastwait) asm volatile("s_waitcnt vmcnt(0)" ::: "memory");
    else          asm volatile("s_waitcnt vmcnt(9)" ::: "memory");
    __builtin_amdgcn_s_barrier();
    asm volatile("" ::: "memory");       // no LDS read hoists above barrier

    const ushort_t* bu = (const ushort_t*)bufp;
    floatx4 S[13];
    #pragma unroll
    for (int t = 0; t < 13; t++) S[t] = (floatx4){0.f, 0.f, 0.f, 0.f};
    #pragma unroll
    for (int kk = 0; kk < 2; kk++)
      #pragma unroll
      for (int t = 0; t < 13; t++) {
        bf16x8 bbv = *(const bf16x8*)&bu[((quad + 4 * kk) * KP + 16 * t + l15) * 8];
        S[t] = __builtin_amdgcn_mfma_f32_16x16x32_bf16(qf[kk], bbv, S[t], 0, 0, 0);
      }

    asm volatile("" ::: "memory");       // no LDS read sinks below barrier
    __builtin_amdgcn_s_barrier();        // all waves done reading bufp
    if (h + 2 < H_) {                    // prefetch 2 heads ahead
      loadq(h + 2, qf);
      stage(h + 2, bufp);
      // keep the 9-op issue cluster together; nothing drifts across softmax
      __builtin_amdgcn_sched_barrier(0);
    }

    // softmax over k (196 valid), accumulate P/rowsum (pure VALU, overlaps DMA)
    #pragma unroll
    for (int r = 0; r < 4; r++) {
      float s = 0.f;
      #pragma unroll
      for (int t = 0; t < 13; t++) {
        float e_ = (t == 12 && l15 >= 4) ? 0.f : __expf(S[t][r]);
        S[t][r] = e_;
        s += e_;
      }
      #pragma unroll
      for (int off = 1; off < 16; off <<= 1) s += __shfl_xor(s, off);
      float inv = 1.f / s;
      #pragma unroll
      for (int t = 0; t < 13; t++) accA[t][r] += S[t][r] * inv;
    }
  };

  // prologue: heads 0 and 1 in flight. Issue-order MUST be {Q0,D0} then
  // {Q1,D1} for the vmcnt(9) count to drain exactly head 0 at the first
  // wait — sched_barrier(0) pins the groups (plain Q loads could otherwise
  // hoist above the LDS-DMA builtins).
  bf16x8 qfA[2], qfB[2];
  loadq(0, qfA); stage(0, ks[0]);
  __builtin_amdgcn_sched_barrier(0);
  loadq(1, qfB); stage(1, ks[1]);
  __builtin_amdgcn_sched_barrier(0);

  #pragma unroll 1
  for (int hh = 0; hh < 6; hh++) {
    headbody(2 * hh,     ks[0], qfA, false);
    headbody(2 * hh + 1, ks[1], qfB, hh == 5);
  }

  // epilogue: transpose accA via LDS (wave-private rows), uint4 stores
  const float s12 = 1.f / 12.f;
  #pragma unroll
  for (int t = 0; t < 13; t++)
    #pragma unroll
    for (int r = 0; r < 4; r++)
      at[(16 * wv + 4 * quad + r) * ATS + 16 * t + l15] = f2bf(accA[t][r] * s12);
  #pragma unroll
  for (int i = 0; i < 7; i++) {
    int e = lane + 64 * i;             // 16 rows x 26 uint4 = 416
    if (e < 416) {
      int row = e / 26, col = e - row * 26;
      uint4 v = *(const uint4*)&at[(16 * wv + row) * ATS + col * 8];
      int qi = qi_b + row;
      if (qi < Q_)
        *(uint4*)(Ah + ((size_t)qi * (N_ * T_) + ntq) * KP + col * 8) = v;
    }
  }
}

// ------------- Stage 2: out[nt,qi,c] = sum_half A_h[qi] @ gather(W_h) ------
// grid (6 c-tiles of 128, 196 qi), block 256. As via DMA (dbuf, skewed
// planes); W gather is wave-private -> ONE barrier per chunk.
__global__ __launch_bounds__(256, 4) void mix_kernel(
    const ushort_t* __restrict__ A1, const ushort_t* __restrict__ A2,
    const float* __restrict__ w1, const float* __restrict__ w2,
    const int* __restrict__ idx, float* __restrict__ out) {
  const int ct = blockIdx.x;   // 0..5
  const int qi = blockIdx.y;   // 0..195
  const int tid  = threadIdx.x;
  const int lane = tid & 63;
  const int wv   = tid >> 6;
  const int quad = lane >> 4;
  const int l15  = lane & 15;
  const int p    = lane >> 2;  // k-pair 0..15
  const int cq   = lane & 3;   // c-chunk slot

  __shared__ __align__(16) char As[2][4 * APLANE];   // 2 x 8448 B
  __shared__ ushort_t Ws[128][40];                   // wave-private rows

  // idx regs: this lane's two k-rows per chunk (clamped; A=0 kills pad cols)
  int idxr0[7], idxr1[7];
  #pragma unroll
  for (int kc = 0; kc < 7; kc++) {
    int off = 32 * kc + 2 * p;
    if (off > 194) off = 194;
    int2 pr = *(const int2*)(idx + (size_t)qi * Q_ + off);
    idxr0[kc] = pr.x; idxr1[kc] = pr.y;
  }

  floatx4 acc[8][2];
  #pragma unroll
  for (int mt = 0; mt < 8; mt++)
    #pragma unroll
    for (int u = 0; u < 2; u++) acc[mt][u] = (floatx4){0.f, 0.f, 0.f, 0.f};

  float4 pw[2][2];   // [k-offset j][c-chunk u]
  const int cbase = ct * 128 + wv * 32;

  // ---- preload chunk 0 ----
  {
    const ushort_t* Ah_ = A1;
    #pragma unroll
    for (int r = 0; r < 2; r++)
      GLD_LDS16(Ah_ + ((size_t)qi * 128 + r * 64 + lane) * KP + wv * 8,
                As[0] + wv * APLANE + r * 1024);
    #pragma unroll
    for (int j = 0; j < 2; j++)
      #pragma unroll
      for (int u = 0; u < 2; u++)
        pw[j][u] = *(const float4*)(w1 + (size_t)(j ? idxr1[0] : idxr0[0]) * C_ +
                                    cbase + (cq + 4 * u) * 4);
  }

  #pragma unroll
  for (int ht = 0; ht < 14; ht++) {
    const int half = ht / 7, kc = ht % 7;
    __syncthreads();                 // As[ht&1] DMA + pw gather drained

    // commit this chunk's W (wave-private -> no barrier needed)
    #pragma unroll
    for (int u = 0; u < 2; u++) {
      const float* f0 = (const float*)&pw[0][u];
      const float* f1 = (const float*)&pw[1][u];
      #pragma unroll
      for (int e = 0; e < 4; e++)
        *(unsigned int*)&Ws[wv * 32 + (cq + 4 * u) * 4 + e][2 * p] = pack2(f0[e], f1[e]);
    }

    // issue next chunk's A-DMA + W-gather (in flight through the MFMA phase)
    if (ht + 1 < 14) {
      const int nh = (ht + 1) / 7, nk = (ht + 1) % 7;
      const ushort_t* Ah_ = nh ? A2 : A1;
      const float* w_ = nh ? w2 : w1;
      #pragma unroll
      for (int r = 0; r < 2; r++)
        GLD_LDS16(Ah_ + ((size_t)qi * 128 + r * 64 + lane) * KP + 32 * nk + wv * 8,
                  As[(ht + 1) & 1] + wv * APLANE + r * 1024);
      int r0 = idxr0[nk], r1 = idxr1[nk];
      #pragma unroll
      for (int u = 0; u < 2; u++) {
        pw[0][u] = *(const float4*)(w_ + (size_t)r0 * C_ + cbase + (cq + 4 * u) * 4);
        pw[1][u] = *(const float4*)(w_ + (size_t)r1 * C_ + cbase + (cq + 4 * u) * 4);
      }
    }

    // MFMA phase: LDS only
    const char* ab = As[ht & 1];
    bf16x8 bfv[2];
    #pragma unroll
    for (int u = 0; u < 2; u++)
      bfv[u] = *(const bf16x8*)&Ws[wv * 32 + 16 * u + l15][8 * quad];
    #pragma unroll
    for (int mt = 0; mt < 8; mt++) {
      bf16x8 a = *(const bf16x8*)(ab + quad * APLANE + (16 * mt + l15) * 16);
      acc[mt][0] = __builtin_amdgcn_mfma_f32_16x16x32_bf16(a, bfv[0], acc[mt][0], 0, 0, 0);
      acc[mt][1] = __builtin_amdgcn_mfma_f32_16x16x32_bf16(a, bfv[1], acc[mt][1], 0, 0, 0);
    }
  }

  #pragma unroll
  for (int u = 0; u < 2; u++) {
    const int c = ct * 128 + 32 * wv + 16 * u + l15;
    #pragma unroll
    for (int mt = 0; mt < 8; mt++)
      #pragma unroll
      for (int r = 0; r < 4; r++) {
        int m = 16 * mt + 4 * quad + r;
        out[((size_t)m * L_ + 1 + qi) * C_ + c] = acc[mt][u][r];
      }
  }
  if (qi == 0) {
    #pragma unroll
    for (int u = 0; u < 2; u++) {
      const int c = ct * 128 + 32 * wv + 16 * u + l15;
      #pragma unroll
      for (int mt = 0; mt < 8; mt++)
        #pragma unroll
        for (int r = 0; r < 4; r++) {
          int m = 16 * mt + 4 * quad + r;
          out[(size_t)m * L_ * C_ + c] = 0.f;
        }
    }
  }
}

extern "C" void kernel_launch(void* const* d_in, const int* in_sizes, int n_in,
                              void* d_out, int out_size, void* d_ws, size_t ws_size,
                              hipStream_t stream) {
  const float* q  = (const float*)d_in[0];
  const float* k  = (const float*)d_in[1];
  const float* w1 = (const float*)d_in[2];
  const float* w2 = (const float*)d_in[3];
  const int* idx  = (const int*)d_in[4];
  float* out = (float*)d_out;

  const size_t plane_tot = (size_t)(N_ * T_) * H_ * ENT;   // uint4 entries
  uint4* qb = (uint4*)d_ws;
  uint4* kb = qb + plane_tot;
  ushort_t* A1 = (ushort_t*)(kb + plane_tot);
  size_t Aelems = (size_t)Q_ * (N_ * T_) * KP;
  ushort_t* A2 = A1 + Aelems;

  // zero A buffers: covers k-pad cols and the empty t-slots
  hipMemsetAsync(A1, 0, Aelems * 2 * sizeof(ushort_t), stream);

  convert_kernel<<<dim3(N_ * T_, H_, 2), 256, 0, stream>>>(q, k, qb, kb);
  attn_kernel<<<dim3(896), 256, 0, stream>>>(qb, kb, A1, A2);
  mix_kernel<<<dim3(6, Q_), 256, 0, stream>>>(A1, A2, w1, w2, idx, out);
}

// Round 4
// 336.549 us; speedup vs baseline: 1.2047x; 1.0053x over previous
//
#include <hip/hip_runtime.h>

#define N_ 16
#define T_ 8
#define L_ 197
#define H_ 12
#define D_ 64
#define Q_ 196
#define C_ 768
#define KP 224          // padded K/pos dimension (7 x 32)
#define ENT 1792        // 8 dchunks * 224 pos, 16B entries per (nt,h) plane
#define ATS 216         // attn epilogue LDS row stride (ushorts)
#define APLANE 2112     // mix: As plane stride bytes (2048 + 64 skew)

typedef unsigned short ushort_t;
typedef __bf16 bf16x8 __attribute__((ext_vector_type(8)));
typedef float floatx4 __attribute__((ext_vector_type(4)));

// async global->LDS, 16B per lane, dst = uniform base + lane*16
#define GLD_LDS16(g, l)                                                    \
  __builtin_amdgcn_global_load_lds(                                        \
      (const __attribute__((address_space(1))) void*)(g),                  \
      (__attribute__((address_space(3))) void*)(l), 16, 0, 0)

static __device__ inline ushort_t f2bf(float x) {
  unsigned int u = __float_as_uint(x);
  u += 0x7fffu + ((u >> 16) & 1u);       // RNE
  return (ushort_t)(u >> 16);
}
static __device__ inline unsigned int pack2(float a, float b) {
  return (unsigned int)f2bf(a) | ((unsigned int)f2bf(b) << 16);
}

// ------------- Pass 0: q,k fp32 -> bf16 planes [nt][h][dc 8][pos 224] ------
// One block per (nt, h, q|k) plane. ALL 14 float4 loads are front-loaded
// into named registers (sched_barrier-pinned) so ~14 HBM ops stay in flight
// per wave — round-3 showed the compiler otherwise sinks them (VGPR=44,
// ~2 in flight, latency-bound at 2 TB/s). launch_bounds(256,4) raises the
// VGPR cap to 128 to hold the payload. Then pack via XOR-swizzled LDS
// (conflict-free both phases) and stream the 28KB plane out contiguously.
__global__ __launch_bounds__(256, 4) void convert_kernel(
    const float* __restrict__ q, const float* __restrict__ k,
    uint4* __restrict__ qb, uint4* __restrict__ kb) {
  const int nt  = blockIdx.x;      // 0..127
  const int h   = blockIdx.y;      // 0..11
  const int inp = blockIdx.z;      // 0 = q, 1 = k
  const int tid = threadIdx.x;

  const float* src = inp ? k : q;
  const float sc = inp ? 1.f : 0.125f;
  uint4* dst = (inp ? kb : qb) + ((size_t)nt * H_ + h) * ENT;

  __shared__ __align__(16) uint4 lds[8 * KP];   // 28 KB: [dc][pos swizzled]

  const float* base = src + ((size_t)nt * L_ + 1) * (H_ * D_) + h * D_;

  // phase 1a: issue all loads (r<6 unconditional; r=6 valid iff tid<32,
  // since 1536+tid < 1568). Static indexing -> registers, no scratch.
  float4 va[7], vb[7];
  #pragma unroll
  for (int r = 0; r < 7; r++) {
    int e = tid + 256 * r;               // < 1792; valid < 1568
    int pos = e >> 3, dc = e & 7;
    if (r < 6 || tid < 32) {
      const float* p = base + (size_t)pos * (H_ * D_) + dc * 8;
      va[r] = *(const float4*)p;
      vb[r] = *(const float4*)(p + 4);
    }
  }
  __builtin_amdgcn_sched_barrier(0);     // keep the 14-load cluster ahead

  // phase 1b: pack + swizzled LDS write (waits retire oldest-first)
  #pragma unroll
  for (int r = 0; r < 7; r++) {
    int e = tid + 256 * r;
    int pos = e >> 3, dc = e & 7;
    if (r < 6 || tid < 32) {
      uint4 o;
      o.x = pack2(va[r].x * sc, va[r].y * sc);
      o.y = pack2(va[r].z * sc, va[r].w * sc);
      o.z = pack2(vb[r].x * sc, vb[r].y * sc);
      o.w = pack2(vb[r].z * sc, vb[r].w * sc);
      lds[dc * KP + ((pos & ~7) | ((pos ^ dc) & 7))] = o;
    }
  }
  __syncthreads();

  // phase 2: contiguous plane store (1 KB per wave per iter); pad pos = 0
  #pragma unroll
  for (int r = 0; r < 7; r++) {
    int e = tid + 256 * r;               // output entry, 0..1791
    int dc = e / KP, pos = e - dc * KP;
    uint4 v;
    if (pos < 196) v = lds[dc * KP + ((pos & ~7) | ((pos ^ dc) & 7))];
    else           v = (uint4){0u, 0u, 0u, 0u};
    dst[e] = v;
  }
}

// ------------- Stage 1: A[qi][nt][k] = mean_h softmax_k(QK^T/8), bf16 ------
// 1D grid 896, XCD-swizzled. K double-buffered in LDS via global_load_lds;
// raw s_barrier + counted vmcnt(9) keeps the next head's DMA (7 loads) and
// Q-frag loads (2) in flight across barriers (T3+T4). Q ping-pongs between
// two named register sets (static indexing only).
__global__ __launch_bounds__(256, 2) void attn_kernel(
    const uint4* __restrict__ qb, const uint4* __restrict__ kb,
    ushort_t* __restrict__ A1, ushort_t* __restrict__ A2) {
  const int lin  = blockIdx.x;          // 0..895
  const int xcd  = lin & 7;
  const int slot = lin >> 3;            // 0..111
  const int g    = (slot >> 2) * 8 + xcd;   // K-group 0..223
  const int b    = slot & 3;            // q-row block of 64
  const int half = g / 112;
  const int nt   = g - half * 112;
  const int n  = nt / 7, tp = nt % 7;
  const int tq = (half == 0) ? tp + 1 : tp;
  const int tk = (half == 0) ? tp     : tp + 1;
  const int ntq = n * T_ + tq;
  const int ntk = n * T_ + tk;

  const uint4* qpl = qb + (size_t)ntq * H_ * ENT;
  const uint4* kpl = kb + (size_t)ntk * H_ * ENT;
  ushort_t* Ah = (half == 0) ? A1 : A2;

  __shared__ __align__(16) uint4 ks[2][ENT];   // 2 x 28 KB double buffer
  ushort_t* at = (ushort_t*)ks;                // epilogue alias (27.6 KB, in ks[0])

  const int tid  = threadIdx.x;
  const int lane = tid & 63;
  const int wv   = tid >> 6;
  const int quad = lane >> 4;
  const int l15  = lane & 15;
  const int qi_b = 64 * b + 16 * wv;

  float accA[13][4];
  #pragma unroll
  for (int t = 0; t < 13; t++)
    #pragma unroll
    for (int r = 0; r < 4; r++) accA[t][r] = 0.f;

  // per-wave K DMA for head h into buffer bufp (7 vmem ops / wave)
  auto stage = [&](int h, uint4* bufp) {
    #pragma unroll
    for (int r = 0; r < 7; r++)
      GLD_LDS16(kpl + (size_t)h * ENT + 256 * r + 64 * wv + lane,
                (char*)bufp + (256 * r + 64 * wv) * 16);
  };
  // Q fragments for head h (2 vmem ops / lane)
  auto loadq = [&](int h, bf16x8* qf) {
    #pragma unroll
    for (int kk = 0; kk < 2; kk++)
      qf[kk] = *(const bf16x8*)&qpl[(size_t)h * ENT + (quad + 4 * kk) * KP + qi_b + l15];
  };

  // one head: wait(own DMA(h)+Q(h) landed, keep next head's 9 in flight) ->
  // barrier -> MFMA from bufp -> barrier -> issue head h+2 into same buffer
  // (parity) -> softmax (overlaps the in-flight DMA).
  auto headbody = [&](int h, uint4* bufp, bf16x8* qf, bool lastwait) {
    if (lastwait) asm volatile("s_waitcnt vmcnt(0)" ::: "memory");
    else          asm volatile("s_waitcnt vmcnt(9)" ::: "memory");
    __builtin_amdgcn_s_barrier();
    asm volatile("" ::: "memory");       // no LDS read hoists above barrier

    const ushort_t* bu = (const ushort_t*)bufp;
    floatx4 S[13];
    #pragma unroll
    for (int t = 0; t < 13; t++) S[t] = (floatx4){0.f, 0.f, 0.f, 0.f};
    #pragma unroll
    for (int kk = 0; kk < 2; kk++)
      #pragma unroll
      for (int t = 0; t < 13; t++) {
        bf16x8 bbv = *(const bf16x8*)&bu[((quad + 4 * kk) * KP + 16 * t + l15) * 8];
        S[t] = __builtin_amdgcn_mfma_f32_16x16x32_bf16(qf[kk], bbv, S[t], 0, 0, 0);
      }

    asm volatile("" ::: "memory");       // no LDS read sinks below barrier
    __builtin_amdgcn_s_barrier();        // all waves done reading bufp
    if (h + 2 < H_) {                    // prefetch 2 heads ahead
      loadq(h + 2, qf);
      stage(h + 2, bufp);
      // keep the 9-op issue cluster together; nothing drifts across softmax
      __builtin_amdgcn_sched_barrier(0);
    }

    // softmax over k (196 valid), accumulate P/rowsum (pure VALU, overlaps DMA)
    #pragma unroll
    for (int r = 0; r < 4; r++) {
      float s = 0.f;
      #pragma unroll
      for (int t = 0; t < 13; t++) {
        float e_ = (t == 12 && l15 >= 4) ? 0.f : __expf(S[t][r]);
        S[t][r] = e_;
        s += e_;
      }
      #pragma unroll
      for (int off = 1; off < 16; off <<= 1) s += __shfl_xor(s, off);
      float inv = 1.f / s;
      #pragma unroll
      for (int t = 0; t < 13; t++) accA[t][r] += S[t][r] * inv;
    }
  };

  // prologue: heads 0 and 1 in flight. Issue-order MUST be {Q0,D0} then
  // {Q1,D1} for the vmcnt(9) count to drain exactly head 0 at the first
  // wait — sched_barrier(0) pins the groups (plain Q loads could otherwise
  // hoist above the LDS-DMA builtins).
  bf16x8 qfA[2], qfB[2];
  loadq(0, qfA); stage(0, ks[0]);
  __builtin_amdgcn_sched_barrier(0);
  loadq(1, qfB); stage(1, ks[1]);
  __builtin_amdgcn_sched_barrier(0);

  #pragma unroll 1
  for (int hh = 0; hh < 6; hh++) {
    headbody(2 * hh,     ks[0], qfA, false);
    headbody(2 * hh + 1, ks[1], qfB, hh == 5);
  }

  // epilogue: transpose accA via LDS (wave-private rows), uint4 stores
  const float s12 = 1.f / 12.f;
  #pragma unroll
  for (int t = 0; t < 13; t++)
    #pragma unroll
    for (int r = 0; r < 4; r++)
      at[(16 * wv + 4 * quad + r) * ATS + 16 * t + l15] = f2bf(accA[t][r] * s12);
  #pragma unroll
  for (int i = 0; i < 7; i++) {
    int e = lane + 64 * i;             // 16 rows x 26 uint4 = 416
    if (e < 416) {
      int row = e / 26, col = e - row * 26;
      uint4 v = *(const uint4*)&at[(16 * wv + row) * ATS + col * 8];
      int qi = qi_b + row;
      if (qi < Q_)
        *(uint4*)(Ah + ((size_t)qi * (N_ * T_) + ntq) * KP + col * 8) = v;
    }
  }
}

// ------------- Stage 2: out[nt,qi,c] = sum_half A_h[qi] @ gather(W_h) ------
// grid (6 c-tiles of 128, 196 qi), block 256. As via DMA (dbuf, skewed
// planes); W gather is wave-private -> ONE barrier per chunk.
__global__ __launch_bounds__(256, 4) void mix_kernel(
    const ushort_t* __restrict__ A1, const ushort_t* __restrict__ A2,
    const float* __restrict__ w1, const float* __restrict__ w2,
    const int* __restrict__ idx, float* __restrict__ out) {
  const int ct = blockIdx.x;   // 0..5
  const int qi = blockIdx.y;   // 0..195
  const int tid  = threadIdx.x;
  const int lane = tid & 63;
  const int wv   = tid >> 6;
  const int quad = lane >> 4;
  const int l15  = lane & 15;
  const int p    = lane >> 2;  // k-pair 0..15
  const int cq   = lane & 3;   // c-chunk slot

  __shared__ __align__(16) char As[2][4 * APLANE];   // 2 x 8448 B
  __shared__ ushort_t Ws[128][40];                   // wave-private rows

  // idx regs: this lane's two k-rows per chunk (clamped; A=0 kills pad cols)
  int idxr0[7], idxr1[7];
  #pragma unroll
  for (int kc = 0; kc < 7; kc++) {
    int off = 32 * kc + 2 * p;
    if (off > 194) off = 194;
    int2 pr = *(const int2*)(idx + (size_t)qi * Q_ + off);
    idxr0[kc] = pr.x; idxr1[kc] = pr.y;
  }

  floatx4 acc[8][2];
  #pragma unroll
  for (int mt = 0; mt < 8; mt++)
    #pragma unroll
    for (int u = 0; u < 2; u++) acc[mt][u] = (floatx4){0.f, 0.f, 0.f, 0.f};

  float4 pw[2][2];   // [k-offset j][c-chunk u]
  const int cbase = ct * 128 + wv * 32;

  // ---- preload chunk 0 ----
  {
    const ushort_t* Ah_ = A1;
    #pragma unroll
    for (int r = 0; r < 2; r++)
      GLD_LDS16(Ah_ + ((size_t)qi * 128 + r * 64 + lane) * KP + wv * 8,
                As[0] + wv * APLANE + r * 1024);
    #pragma unroll
    for (int j = 0; j < 2; j++)
      #pragma unroll
      for (int u = 0; u < 2; u++)
        pw[j][u] = *(const float4*)(w1 + (size_t)(j ? idxr1[0] : idxr0[0]) * C_ +
                                    cbase + (cq + 4 * u) * 4);
  }

  #pragma unroll
  for (int ht = 0; ht < 14; ht++) {
    const int half = ht / 7, kc = ht % 7;
    __syncthreads();                 // As[ht&1] DMA + pw gather drained

    // commit this chunk's W (wave-private -> no barrier needed)
    #pragma unroll
    for (int u = 0; u < 2; u++) {
      const float* f0 = (const float*)&pw[0][u];
      const float* f1 = (const float*)&pw[1][u];
      #pragma unroll
      for (int e = 0; e < 4; e++)
        *(unsigned int*)&Ws[wv * 32 + (cq + 4 * u) * 4 + e][2 * p] = pack2(f0[e], f1[e]);
    }

    // issue next chunk's A-DMA + W-gather (in flight through the MFMA phase)
    if (ht + 1 < 14) {
      const int nh = (ht + 1) / 7, nk = (ht + 1) % 7;
      const ushort_t* Ah_ = nh ? A2 : A1;
      const float* w_ = nh ? w2 : w1;
      #pragma unroll
      for (int r = 0; r < 2; r++)
        GLD_LDS16(Ah_ + ((size_t)qi * 128 + r * 64 + lane) * KP + 32 * nk + wv * 8,
                  As[(ht + 1) & 1] + wv * APLANE + r * 1024);
      int r0 = idxr0[nk], r1 = idxr1[nk];
      #pragma unroll
      for (int u = 0; u < 2; u++) {
        pw[0][u] = *(const float4*)(w_ + (size_t)r0 * C_ + cbase + (cq + 4 * u) * 4);
        pw[1][u] = *(const float4*)(w_ + (size_t)r1 * C_ + cbase + (cq + 4 * u) * 4);
      }
    }

    // MFMA phase: LDS only
    const char* ab = As[ht & 1];
    bf16x8 bfv[2];
    #pragma unroll
    for (int u = 0; u < 2; u++)
      bfv[u] = *(const bf16x8*)&Ws[wv * 32 + 16 * u + l15][8 * quad];
    #pragma unroll
    for (int mt = 0; mt < 8; mt++) {
      bf16x8 a = *(const bf16x8*)(ab + quad * APLANE + (16 * mt + l15) * 16);
      acc[mt][0] = __builtin_amdgcn_mfma_f32_16x16x32_bf16(a, bfv[0], acc[mt][0], 0, 0, 0);
      acc[mt][1] = __builtin_amdgcn_mfma_f32_16x16x32_bf16(a, bfv[1], acc[mt][1], 0, 0, 0);
    }
  }

  #pragma unroll
  for (int u = 0; u < 2; u++) {
    const int c = ct * 128 + 32 * wv + 16 * u + l15;
    #pragma unroll
    for (int mt = 0; mt < 8; mt++)
      #pragma unroll
      for (int r = 0; r < 4; r++) {
        int m = 16 * mt + 4 * quad + r;
        out[((size_t)m * L_ + 1 + qi) * C_ + c] = acc[mt][u][r];
      }
  }
  if (qi == 0) {
    #pragma unroll
    for (int u = 0; u < 2; u++) {
      const int c = ct * 128 + 32 * wv + 16 * u + l15;
      #pragma unroll
      for (int mt = 0; mt < 8; mt++)
        #pragma unroll
        for (int r = 0; r < 4; r++) {
          int m = 16 * mt + 4 * quad + r;
          out[(size_t)m * L_ * C_ + c] = 0.f;
        }
    }
  }
}

extern "C" void kernel_launch(void* const* d_in, const int* in_sizes, int n_in,
                              void* d_out, int out_size, void* d_ws, size_t ws_size,
                              hipStream_t stream) {
  const float* q  = (const float*)d_in[0];
  const float* k  = (const float*)d_in[1];
  const float* w1 = (const float*)d_in[2];
  const float* w2 = (const float*)d_in[3];
  const int* idx  = (const int*)d_in[4];
  float* out = (float*)d_out;

  const size_t plane_tot = (size_t)(N_ * T_) * H_ * ENT;   // uint4 entries
  uint4* qb = (uint4*)d_ws;
  uint4* kb = qb + plane_tot;
  ushort_t* A1 = (ushort_t*)(kb + plane_tot);
  size_t Aelems = (size_t)Q_ * (N_ * T_) * KP;
  ushort_t* A2 = A1 + Aelems;

  // zero A buffers: covers k-pad cols and the empty t-slots
  hipMemsetAsync(A1, 0, Aelems * 2 * sizeof(ushort_t), stream);

  convert_kernel<<<dim3(N_ * T_, H_, 2), 256, 0, stream>>>(q, k, qb, kb);
  attn_kernel<<<dim3(896), 256, 0, stream>>>(qb, kb, A1, A2);
  mix_kernel<<<dim3(6, Q_), 256, 0, stream>>>(A1, A2, w1, w2, idx, out);
}